// Round 1
// baseline (538.334 us; speedup 1.0000x reference)
//
#include <hip/hip_runtime.h>
#include <hip/hip_bf16.h>
#include <math.h>

#define BB 16
#define NTOK 1024
#define CDIM 256
#define HEADS 8
#define HD 32

// ---------------------------------------------------------------------------
// Per-query angle bias: bias[b][h][n] = 1 + sigmoid(angle_table[bin(b,n)][h])
// ---------------------------------------------------------------------------
__global__ __launch_bounds__(256) void bias_kernel(
    const float* __restrict__ affine, const float* __restrict__ atab,
    float* __restrict__ bias) {
  int idx = blockIdx.x * 256 + threadIdx.x;  // b*N + n
  if (idx >= BB * NTOK) return;
  int b = idx >> 10, n = idx & (NTOK - 1);
  float cx = (float)(n & 31);   // x = n % W
  float cy = (float)(n >> 5);   // y = n / W
  const float* A = affine + b * 6;
  float egx = fmaf(A[0], 16.f, fmaf(A[1], 16.f, A[2]));
  float egy = fmaf(A[3], 16.f, fmaf(A[4], 16.f, A[5]));
  float ang = atan2f(cy - egy, cx - egx);
  float t = (ang + 3.14159265358979323846f) *
            (1.f / (2.f * 3.14159265358979323846f)) * 4.f;
  int bin = (int)t;
  bin = bin < 0 ? 0 : (bin > 4 ? 4 : bin);
  for (int h = 0; h < HEADS; ++h) {
    float a = atab[bin * HEADS + h];
    float s = 1.f / (1.f + __expf(-a));
    bias[((size_t)b * HEADS + h) * NTOK + n] = 1.f + s;
  }
}

// ---------------------------------------------------------------------------
// Fused QKV projection: X(16384,256) @ [Wq | Wkv](256,768) + bias, scattered
// into q/k/v laid out (B, h, N, d).
// ---------------------------------------------------------------------------
__global__ __launch_bounds__(256) void gemm_qkv(
    const float* __restrict__ X, const float* __restrict__ Wq,
    const float* __restrict__ bq, const float* __restrict__ Wkv,
    const float* __restrict__ bkv, float* __restrict__ qb,
    float* __restrict__ kb, float* __restrict__ vb) {
  __shared__ float Xs[64][65];
  __shared__ float Ws[64][65];
  int tid = threadIdx.x;
  int m0 = blockIdx.y * 64;
  int j0 = blockIdx.x * 64;
  const float* Wsrc;
  int wstride, jo;
  if (j0 < CDIM) { Wsrc = Wq; wstride = CDIM; jo = j0; }
  else           { Wsrc = Wkv; wstride = 2 * CDIM; jo = j0 - CDIM; }
  int lr = tid >> 4;          // 0..15
  int lc = (tid & 15) * 4;    // 0..60
  int tr = tid >> 4, tc = tid & 15;
  float acc[4][4] = {};
  for (int k0 = 0; k0 < CDIM; k0 += 64) {
    __syncthreads();
#pragma unroll
    for (int rr = 0; rr < 4; ++rr) {
      int row = lr + rr * 16;
      float4 xv = *(const float4*)(X + (size_t)(m0 + row) * CDIM + k0 + lc);
      Xs[row][lc] = xv.x; Xs[row][lc + 1] = xv.y;
      Xs[row][lc + 2] = xv.z; Xs[row][lc + 3] = xv.w;
      float4 wv = *(const float4*)(Wsrc + (size_t)(k0 + row) * wstride + jo + lc);
      Ws[row][lc] = wv.x; Ws[row][lc + 1] = wv.y;
      Ws[row][lc + 2] = wv.z; Ws[row][lc + 3] = wv.w;
    }
    __syncthreads();
#pragma unroll
    for (int kk = 0; kk < 64; ++kk) {
      float a0 = Xs[tr * 4 + 0][kk], a1 = Xs[tr * 4 + 1][kk];
      float a2 = Xs[tr * 4 + 2][kk], a3 = Xs[tr * 4 + 3][kk];
      float b0 = Ws[kk][tc * 4 + 0], b1 = Ws[kk][tc * 4 + 1];
      float b2 = Ws[kk][tc * 4 + 2], b3 = Ws[kk][tc * 4 + 3];
      acc[0][0] = fmaf(a0, b0, acc[0][0]); acc[0][1] = fmaf(a0, b1, acc[0][1]);
      acc[0][2] = fmaf(a0, b2, acc[0][2]); acc[0][3] = fmaf(a0, b3, acc[0][3]);
      acc[1][0] = fmaf(a1, b0, acc[1][0]); acc[1][1] = fmaf(a1, b1, acc[1][1]);
      acc[1][2] = fmaf(a1, b2, acc[1][2]); acc[1][3] = fmaf(a1, b3, acc[1][3]);
      acc[2][0] = fmaf(a2, b0, acc[2][0]); acc[2][1] = fmaf(a2, b1, acc[2][1]);
      acc[2][2] = fmaf(a2, b2, acc[2][2]); acc[2][3] = fmaf(a2, b3, acc[2][3]);
      acc[3][0] = fmaf(a3, b0, acc[3][0]); acc[3][1] = fmaf(a3, b1, acc[3][1]);
      acc[3][2] = fmaf(a3, b2, acc[3][2]); acc[3][3] = fmaf(a3, b3, acc[3][3]);
    }
  }
#pragma unroll
  for (int i = 0; i < 4; ++i) {
    int m = m0 + tr * 4 + i;
    int b = m >> 10, n = m & (NTOK - 1);
#pragma unroll
    for (int j = 0; j < 4; ++j) {
      int jg = j0 + tc * 4 + j;
      float val = acc[i][j];
      if (jg < CDIM) {
        int h = jg >> 5, d = jg & 31;
        qb[(((size_t)b * HEADS + h) * NTOK + n) * HD + d] = val + bq[jg];
      } else {
        int c2 = jg - CDIM;
        float vv = val + bkv[c2];
        if (c2 < CDIM) {
          int h = c2 >> 5, d = c2 & 31;
          kb[(((size_t)b * HEADS + h) * NTOK + n) * HD + d] = vv;
        } else {
          int c3 = c2 - CDIM;
          int h = c3 >> 5, d = c3 & 31;
          vb[(((size_t)b * HEADS + h) * NTOK + n) * HD + d] = vv;
        }
      }
    }
  }
}

// ---------------------------------------------------------------------------
// Flash-style attention. One block per (b, h, 64-query tile).
// logits = (q*scale*bias[q]) . k + mask[b%4][q][k]; online softmax; O += P V.
// ---------------------------------------------------------------------------
__global__ __launch_bounds__(256) void attn_kernel(
    const float* __restrict__ q, const float* __restrict__ k,
    const float* __restrict__ v, const float* __restrict__ bias,
    const float* __restrict__ mask, float* __restrict__ o) {
  __shared__ float Qs[64][33];
  __shared__ float Ks[64][33];
  __shared__ float Vs[64][34];
  __shared__ float Ps[64][68];
  int tid = threadIdx.x;
  int qt = blockIdx.x;  // 0..15
  int h = blockIdx.y;   // 0..7
  int b = blockIdx.z;   // 0..15
  int q0 = qt * 64;
  const float* qp = q + ((size_t)(b * HEADS + h) * NTOK + q0) * HD;
  const float* kp = k + (size_t)(b * HEADS + h) * NTOK * HD;
  const float* vp = v + (size_t)(b * HEADS + h) * NTOK * HD;
  const float* maskp = mask + (size_t)(b & 3) * NTOK * NTOK;
  const float* biasp = bias + (size_t)(b * HEADS + h) * NTOK + q0;
  const float scale = 0.17677669529663687f;  // 32^-0.5

  {  // load Q tile, folding scale*bias[row] into each row
    int row = tid >> 2;
    int col = (tid & 3) * 8;
    float bs = biasp[row] * scale;
    float4 a = *(const float4*)(qp + row * HD + col);
    float4 c = *(const float4*)(qp + row * HD + col + 4);
    Qs[row][col + 0] = a.x * bs; Qs[row][col + 1] = a.y * bs;
    Qs[row][col + 2] = a.z * bs; Qs[row][col + 3] = a.w * bs;
    Qs[row][col + 4] = c.x * bs; Qs[row][col + 5] = c.y * bs;
    Qs[row][col + 6] = c.z * bs; Qs[row][col + 7] = c.w * bs;
  }

  int tr = tid >> 4, tc = tid & 15;
  float mstate[4], lstate[4], acc[4][2];
#pragma unroll
  for (int i = 0; i < 4; ++i) {
    mstate[i] = -INFINITY; lstate[i] = 0.f;
    acc[i][0] = 0.f; acc[i][1] = 0.f;
  }
  int dc = tc * 2;

  for (int kt = 0; kt < 16; ++kt) {
    int k0 = kt * 64;
    __syncthreads();
    {  // load K, V tiles
      int row = tid >> 2;
      int col = (tid & 3) * 8;
      float4 a = *(const float4*)(kp + (size_t)(k0 + row) * HD + col);
      float4 c = *(const float4*)(kp + (size_t)(k0 + row) * HD + col + 4);
      Ks[row][col + 0] = a.x; Ks[row][col + 1] = a.y;
      Ks[row][col + 2] = a.z; Ks[row][col + 3] = a.w;
      Ks[row][col + 4] = c.x; Ks[row][col + 5] = c.y;
      Ks[row][col + 6] = c.z; Ks[row][col + 7] = c.w;
      float4 av = *(const float4*)(vp + (size_t)(k0 + row) * HD + col);
      float4 cv = *(const float4*)(vp + (size_t)(k0 + row) * HD + col + 4);
      Vs[row][col + 0] = av.x; Vs[row][col + 1] = av.y;
      Vs[row][col + 2] = av.z; Vs[row][col + 3] = av.w;
      Vs[row][col + 4] = cv.x; Vs[row][col + 5] = cv.y;
      Vs[row][col + 6] = cv.z; Vs[row][col + 7] = cv.w;
    }
    __syncthreads();

    float s[4][4] = {};
#pragma unroll
    for (int kk = 0; kk < HD; ++kk) {
      float a0 = Qs[tr * 4 + 0][kk], a1 = Qs[tr * 4 + 1][kk];
      float a2 = Qs[tr * 4 + 2][kk], a3 = Qs[tr * 4 + 3][kk];
      float b0 = Ks[tc * 4 + 0][kk], b1 = Ks[tc * 4 + 1][kk];
      float b2 = Ks[tc * 4 + 2][kk], b3 = Ks[tc * 4 + 3][kk];
      s[0][0] = fmaf(a0, b0, s[0][0]); s[0][1] = fmaf(a0, b1, s[0][1]);
      s[0][2] = fmaf(a0, b2, s[0][2]); s[0][3] = fmaf(a0, b3, s[0][3]);
      s[1][0] = fmaf(a1, b0, s[1][0]); s[1][1] = fmaf(a1, b1, s[1][1]);
      s[1][2] = fmaf(a1, b2, s[1][2]); s[1][3] = fmaf(a1, b3, s[1][3]);
      s[2][0] = fmaf(a2, b0, s[2][0]); s[2][1] = fmaf(a2, b1, s[2][1]);
      s[2][2] = fmaf(a2, b2, s[2][2]); s[2][3] = fmaf(a2, b3, s[2][3]);
      s[3][0] = fmaf(a3, b0, s[3][0]); s[3][1] = fmaf(a3, b1, s[3][1]);
      s[3][2] = fmaf(a3, b2, s[3][2]); s[3][3] = fmaf(a3, b3, s[3][3]);
    }

#pragma unroll
    for (int i = 0; i < 4; ++i) {  // + mask, online softmax row i
      float4 mv = *(const float4*)(maskp + (size_t)(q0 + tr * 4 + i) * NTOK +
                                   k0 + tc * 4);
      s[i][0] += mv.x; s[i][1] += mv.y; s[i][2] += mv.z; s[i][3] += mv.w;
      float mx = fmaxf(fmaxf(s[i][0], s[i][1]), fmaxf(s[i][2], s[i][3]));
#pragma unroll
      for (int off = 1; off < 16; off <<= 1)
        mx = fmaxf(mx, __shfl_xor(mx, off, 16));
      float mnew = fmaxf(mstate[i], mx);
      float corr = __expf(mstate[i] - mnew);
      mstate[i] = mnew;
      float p0 = __expf(s[i][0] - mnew), p1 = __expf(s[i][1] - mnew);
      float p2 = __expf(s[i][2] - mnew), p3 = __expf(s[i][3] - mnew);
      float rs = (p0 + p1) + (p2 + p3);
#pragma unroll
      for (int off = 1; off < 16; off <<= 1)
        rs += __shfl_xor(rs, off, 16);
      lstate[i] = lstate[i] * corr + rs;
      acc[i][0] *= corr; acc[i][1] *= corr;
      *(float4*)&Ps[tr * 4 + i][tc * 4] = make_float4(p0, p1, p2, p3);
    }
    __syncthreads();

#pragma unroll 8
    for (int kk = 0; kk < 64; ++kk) {  // O += P V
      float2 vv = *(const float2*)&Vs[kk][dc];
      float pp0 = Ps[tr * 4 + 0][kk], pp1 = Ps[tr * 4 + 1][kk];
      float pp2 = Ps[tr * 4 + 2][kk], pp3 = Ps[tr * 4 + 3][kk];
      acc[0][0] = fmaf(pp0, vv.x, acc[0][0]); acc[0][1] = fmaf(pp0, vv.y, acc[0][1]);
      acc[1][0] = fmaf(pp1, vv.x, acc[1][0]); acc[1][1] = fmaf(pp1, vv.y, acc[1][1]);
      acc[2][0] = fmaf(pp2, vv.x, acc[2][0]); acc[2][1] = fmaf(pp2, vv.y, acc[2][1]);
      acc[3][0] = fmaf(pp3, vv.x, acc[3][0]); acc[3][1] = fmaf(pp3, vv.y, acc[3][1]);
    }
  }

#pragma unroll
  for (int i = 0; i < 4; ++i) {
    int n = q0 + tr * 4 + i;
    float inv = 1.f / lstate[i];
    float2 r = make_float2(acc[i][0] * inv, acc[i][1] * inv);
    *(float2*)(o + ((size_t)b * NTOK + n) * CDIM + h * HD + dc) = r;
  }
}

// ---------------------------------------------------------------------------
// Output projection: aout(16384,256) @ Wp(256,256) + bp -> out
// ---------------------------------------------------------------------------
__global__ __launch_bounds__(256) void gemm_out(
    const float* __restrict__ X, const float* __restrict__ W,
    const float* __restrict__ bp, float* __restrict__ out) {
  __shared__ float Xs[64][65];
  __shared__ float Ws[64][65];
  int tid = threadIdx.x;
  int m0 = blockIdx.y * 64;
  int j0 = blockIdx.x * 64;
  int lr = tid >> 4;
  int lc = (tid & 15) * 4;
  int tr = tid >> 4, tc = tid & 15;
  float acc[4][4] = {};
  for (int k0 = 0; k0 < CDIM; k0 += 64) {
    __syncthreads();
#pragma unroll
    for (int rr = 0; rr < 4; ++rr) {
      int row = lr + rr * 16;
      float4 xv = *(const float4*)(X + (size_t)(m0 + row) * CDIM + k0 + lc);
      Xs[row][lc] = xv.x; Xs[row][lc + 1] = xv.y;
      Xs[row][lc + 2] = xv.z; Xs[row][lc + 3] = xv.w;
      float4 wv = *(const float4*)(W + (size_t)(k0 + row) * CDIM + j0 + lc);
      Ws[row][lc] = wv.x; Ws[row][lc + 1] = wv.y;
      Ws[row][lc + 2] = wv.z; Ws[row][lc + 3] = wv.w;
    }
    __syncthreads();
#pragma unroll
    for (int kk = 0; kk < 64; ++kk) {
      float a0 = Xs[tr * 4 + 0][kk], a1 = Xs[tr * 4 + 1][kk];
      float a2 = Xs[tr * 4 + 2][kk], a3 = Xs[tr * 4 + 3][kk];
      float b0 = Ws[kk][tc * 4 + 0], b1 = Ws[kk][tc * 4 + 1];
      float b2 = Ws[kk][tc * 4 + 2], b3 = Ws[kk][tc * 4 + 3];
      acc[0][0] = fmaf(a0, b0, acc[0][0]); acc[0][1] = fmaf(a0, b1, acc[0][1]);
      acc[0][2] = fmaf(a0, b2, acc[0][2]); acc[0][3] = fmaf(a0, b3, acc[0][3]);
      acc[1][0] = fmaf(a1, b0, acc[1][0]); acc[1][1] = fmaf(a1, b1, acc[1][1]);
      acc[1][2] = fmaf(a1, b2, acc[1][2]); acc[1][3] = fmaf(a1, b3, acc[1][3]);
      acc[2][0] = fmaf(a2, b0, acc[2][0]); acc[2][1] = fmaf(a2, b1, acc[2][1]);
      acc[2][2] = fmaf(a2, b2, acc[2][2]); acc[2][3] = fmaf(a2, b3, acc[2][3]);
      acc[3][0] = fmaf(a3, b0, acc[3][0]); acc[3][1] = fmaf(a3, b1, acc[3][1]);
      acc[3][2] = fmaf(a3, b2, acc[3][2]); acc[3][3] = fmaf(a3, b3, acc[3][3]);
    }
  }
#pragma unroll
  for (int i = 0; i < 4; ++i) {
    int m = m0 + tr * 4 + i;
#pragma unroll
    for (int j = 0; j < 4; ++j) {
      int jg = j0 + tc * 4 + j;
      out[(size_t)m * CDIM + jg] = acc[i][j] + bp[jg];
    }
  }
}

// ---------------------------------------------------------------------------
extern "C" void kernel_launch(void* const* d_in, const int* in_sizes, int n_in,
                              void* d_out, int out_size, void* d_ws,
                              size_t ws_size, hipStream_t stream) {
  const float* x = (const float*)d_in[0];
  const float* mask = (const float*)d_in[1];
  const float* affine = (const float*)d_in[2];
  const float* Wq = (const float*)d_in[3];
  const float* bq = (const float*)d_in[4];
  const float* Wkv = (const float*)d_in[5];
  const float* bkv = (const float*)d_in[6];
  const float* Wp = (const float*)d_in[7];
  const float* bp = (const float*)d_in[8];
  const float* atab = (const float*)d_in[9];
  float* out = (float*)d_out;

  const size_t bhnd = (size_t)BB * HEADS * NTOK * HD;  // 4,194,304
  float* qb = (float*)d_ws;
  float* kb = qb + bhnd;
  float* vb = kb + bhnd;
  float* aout = vb + bhnd;
  float* bias = aout + (size_t)BB * NTOK * CDIM;

  bias_kernel<<<64, 256, 0, stream>>>(affine, atab, bias);
  gemm_qkv<<<dim3(12, 256), 256, 0, stream>>>(x, Wq, bq, Wkv, bkv, qb, kb, vb);
  attn_kernel<<<dim3(16, 8, 16), 256, 0, stream>>>(qb, kb, vb, bias, mask, aout);
  gemm_out<<<dim3(4, 256), 256, 0, stream>>>(aout, Wp, bp, out);
}

// Round 2
// 369.914 us; speedup vs baseline: 1.4553x; 1.4553x over previous
//
#include <hip/hip_runtime.h>
#include <hip/hip_bf16.h>
#include <math.h>

#define BB 16
#define NTOK 1024
#define CDIM 256
#define HEADS 8
#define HD 32

typedef __attribute__((ext_vector_type(8))) __bf16 bf16x8;
typedef __attribute__((ext_vector_type(8))) unsigned short u16x8;
typedef __attribute__((ext_vector_type(4))) float f32x4;

// Split fp32 into bf16 hi (truncation) + bf16 lo (truncation of residual).
// hi + lo reproduces f to ~2^-16 relative.
__device__ __forceinline__ void split_bf(float f, unsigned short& hi,
                                         unsigned short& lo) {
  unsigned u = __float_as_uint(f);
  hi = (unsigned short)(u >> 16);
  float fl = f - __uint_as_float(u & 0xFFFF0000u);
  lo = (unsigned short)(__float_as_uint(fl) >> 16);
}

__device__ __forceinline__ bf16x8 ldb8(const unsigned short* p) {
  return *reinterpret_cast<const bf16x8*>(p);
}

// ---------------------------------------------------------------------------
// Per-query angle bias: bias[b][h][n] = 1 + sigmoid(angle_table[bin(b,n)][h])
// ---------------------------------------------------------------------------
__global__ __launch_bounds__(256) void bias_kernel(
    const float* __restrict__ affine, const float* __restrict__ atab,
    float* __restrict__ bias) {
  int idx = blockIdx.x * 256 + threadIdx.x;  // b*N + n
  if (idx >= BB * NTOK) return;
  int b = idx >> 10, n = idx & (NTOK - 1);
  float cx = (float)(n & 31);
  float cy = (float)(n >> 5);
  const float* A = affine + b * 6;
  float egx = fmaf(A[0], 16.f, fmaf(A[1], 16.f, A[2]));
  float egy = fmaf(A[3], 16.f, fmaf(A[4], 16.f, A[5]));
  float ang = atan2f(cy - egy, cx - egx);
  float t = (ang + 3.14159265358979323846f) *
            (1.f / (2.f * 3.14159265358979323846f)) * 4.f;
  int bin = (int)t;
  bin = bin < 0 ? 0 : (bin > 4 ? 4 : bin);
  for (int h = 0; h < HEADS; ++h) {
    float a = atab[bin * HEADS + h];
    float s = 1.f / (1.f + __expf(-a));
    bias[((size_t)b * HEADS + h) * NTOK + n] = 1.f + s;
  }
}

// ---------------------------------------------------------------------------
// Fused QKV projection (fp32 compute). Epilogue emits bf16 hi/lo splits:
//  qhi/qlo: (B,h,N,32)  value = (x@Wq+bq) * scale * bias[b,h,n]
//  khi/klo: (B,h,N,32)
//  vthi/vtlo: (B,h,32,N)  (V transposed for the PV B-operand)
// ---------------------------------------------------------------------------
__global__ __launch_bounds__(256) void gemm_qkv(
    const float* __restrict__ X, const float* __restrict__ Wq,
    const float* __restrict__ bq, const float* __restrict__ Wkv,
    const float* __restrict__ bkv, const float* __restrict__ bias,
    unsigned short* __restrict__ qhi, unsigned short* __restrict__ qlo,
    unsigned short* __restrict__ khi, unsigned short* __restrict__ klo,
    unsigned short* __restrict__ vthi, unsigned short* __restrict__ vtlo) {
  __shared__ float Xs[64][65];
  __shared__ float Ws[64][65];
  int tid = threadIdx.x;
  int m0 = blockIdx.y * 64;
  int j0 = blockIdx.x * 64;
  const float* Wsrc;
  int wstride, jo;
  if (j0 < CDIM) { Wsrc = Wq; wstride = CDIM; jo = j0; }
  else           { Wsrc = Wkv; wstride = 2 * CDIM; jo = j0 - CDIM; }
  int lr = tid >> 4;
  int lc = (tid & 15) * 4;
  int tr = tid >> 4, tc = tid & 15;
  float acc[4][4] = {};
  for (int k0 = 0; k0 < CDIM; k0 += 64) {
    __syncthreads();
#pragma unroll
    for (int rr = 0; rr < 4; ++rr) {
      int row = lr + rr * 16;
      float4 xv = *(const float4*)(X + (size_t)(m0 + row) * CDIM + k0 + lc);
      Xs[row][lc] = xv.x; Xs[row][lc + 1] = xv.y;
      Xs[row][lc + 2] = xv.z; Xs[row][lc + 3] = xv.w;
      float4 wv = *(const float4*)(Wsrc + (size_t)(k0 + row) * wstride + jo + lc);
      Ws[row][lc] = wv.x; Ws[row][lc + 1] = wv.y;
      Ws[row][lc + 2] = wv.z; Ws[row][lc + 3] = wv.w;
    }
    __syncthreads();
#pragma unroll
    for (int kk = 0; kk < 64; ++kk) {
      float a0 = Xs[tr * 4 + 0][kk], a1 = Xs[tr * 4 + 1][kk];
      float a2 = Xs[tr * 4 + 2][kk], a3 = Xs[tr * 4 + 3][kk];
      float b0 = Ws[kk][tc * 4 + 0], b1 = Ws[kk][tc * 4 + 1];
      float b2 = Ws[kk][tc * 4 + 2], b3 = Ws[kk][tc * 4 + 3];
      acc[0][0] = fmaf(a0, b0, acc[0][0]); acc[0][1] = fmaf(a0, b1, acc[0][1]);
      acc[0][2] = fmaf(a0, b2, acc[0][2]); acc[0][3] = fmaf(a0, b3, acc[0][3]);
      acc[1][0] = fmaf(a1, b0, acc[1][0]); acc[1][1] = fmaf(a1, b1, acc[1][1]);
      acc[1][2] = fmaf(a1, b2, acc[1][2]); acc[1][3] = fmaf(a1, b3, acc[1][3]);
      acc[2][0] = fmaf(a2, b0, acc[2][0]); acc[2][1] = fmaf(a2, b1, acc[2][1]);
      acc[2][2] = fmaf(a2, b2, acc[2][2]); acc[2][3] = fmaf(a2, b3, acc[2][3]);
      acc[3][0] = fmaf(a3, b0, acc[3][0]); acc[3][1] = fmaf(a3, b1, acc[3][1]);
      acc[3][2] = fmaf(a3, b2, acc[3][2]); acc[3][3] = fmaf(a3, b3, acc[3][3]);
    }
  }
  const float scale = 0.17677669529663687f;  // 32^-0.5
#pragma unroll
  for (int i = 0; i < 4; ++i) {
    int m = m0 + tr * 4 + i;
    int b = m >> 10, n = m & (NTOK - 1);
#pragma unroll
    for (int j = 0; j < 4; ++j) {
      int jg = j0 + tc * 4 + j;
      float val = acc[i][j];
      unsigned short hi, lo;
      if (jg < CDIM) {
        int h = jg >> 5, d = jg & 31;
        size_t idx = (((size_t)b * HEADS + h) * NTOK + n) * HD + d;
        float s = (val + bq[jg]) * scale * bias[((size_t)b * HEADS + h) * NTOK + n];
        split_bf(s, hi, lo);
        qhi[idx] = hi; qlo[idx] = lo;
      } else {
        int c2 = jg - CDIM;
        float vv = val + bkv[c2];
        if (c2 < CDIM) {
          int h = c2 >> 5, d = c2 & 31;
          size_t idx = (((size_t)b * HEADS + h) * NTOK + n) * HD + d;
          split_bf(vv, hi, lo);
          khi[idx] = hi; klo[idx] = lo;
        } else {
          int c3 = c2 - CDIM;
          int h = c3 >> 5, d = c3 & 31;
          size_t idxT = (((size_t)b * HEADS + h) * HD + d) * NTOK + n;
          split_bf(vv, hi, lo);
          vthi[idxT] = hi; vtlo[idxT] = lo;
        }
      }
    }
  }
}

// ---------------------------------------------------------------------------
// MFMA flash attention. Block = (64-query tile, h, b), 4 waves, each wave
// owns 16 queries x all 1024 keys. Split-bf16 (hi+lo) MFMA: 3 mfma per
// logical 16x16x32 product. Softmax fp32 in registers; P staged f32 in
// wave-private LDS stripe (no __syncthreads anywhere).
// Fragment maps (mfma_f32_16x16x32_bf16):
//   A: row=l&15, k=8*(l>>4)+j   B: col=l&15, k=8*(l>>4)+j
//   D: col=l&15, row=4*(l>>4)+r
// ---------------------------------------------------------------------------
__global__ __launch_bounds__(256) void attn_mfma(
    const unsigned short* __restrict__ qhi, const unsigned short* __restrict__ qlo,
    const unsigned short* __restrict__ khi, const unsigned short* __restrict__ klo,
    const unsigned short* __restrict__ vthi, const unsigned short* __restrict__ vtlo,
    const float* __restrict__ mask, float* __restrict__ o) {
  __shared__ __align__(16) float Ps[64][68];
  int tid = threadIdx.x;
  int w = tid >> 6;        // wave 0..3
  int l = tid & 63;        // lane
  int row16 = l & 15;
  int grp = l >> 4;        // 0..3
  int qt = blockIdx.x, h = blockIdx.y, b = blockIdx.z;
  int q0 = qt * 64;
  int bh = b * HEADS + h;

  // Q A-fragments (hi/lo), loaded once
  size_t qidx = (((size_t)bh * NTOK) + q0 + w * 16 + row16) * HD + grp * 8;
  bf16x8 aqh = ldb8(qhi + qidx);
  bf16x8 aql = ldb8(qlo + qidx);

  const unsigned short* kbase_hi = khi + (size_t)bh * NTOK * HD;
  const unsigned short* kbase_lo = klo + (size_t)bh * NTOK * HD;
  const unsigned short* vbase_hi = vthi + (size_t)bh * HD * NTOK;
  const unsigned short* vbase_lo = vtlo + (size_t)bh * HD * NTOK;
  const float* mrow = mask + (size_t)(b & 3) * NTOK * NTOK +
                      (size_t)(q0 + w * 16 + grp * 4) * NTOK + row16;

  f32x4 accd[2];
  accd[0] = (f32x4){0.f, 0.f, 0.f, 0.f};
  accd[1] = (f32x4){0.f, 0.f, 0.f, 0.f};
  float mst[4] = {-INFINITY, -INFINITY, -INFINITY, -INFINITY};
  float lst[4] = {0.f, 0.f, 0.f, 0.f};
  const f32x4 zero4 = (f32x4){0.f, 0.f, 0.f, 0.f};

  for (int kt = 0; kt < 16; ++kt) {
    int k0 = kt * 64;
    // ---- QK^T: 4 key fragments of 16 keys
    f32x4 s[4];
#pragma unroll
    for (int f = 0; f < 4; ++f) {
      size_t kidx = ((size_t)(k0 + f * 16 + row16)) * HD + grp * 8;
      bf16x8 kh = ldb8(kbase_hi + kidx);
      bf16x8 kl2 = ldb8(kbase_lo + kidx);
      f32x4 t = __builtin_amdgcn_mfma_f32_16x16x32_bf16(aqh, kh, zero4, 0, 0, 0);
      t = __builtin_amdgcn_mfma_f32_16x16x32_bf16(aql, kh, t, 0, 0, 0);
      t = __builtin_amdgcn_mfma_f32_16x16x32_bf16(aqh, kl2, t, 0, 0, 0);
      s[f] = t;
    }
    // ---- +mask, online softmax (per q-row r), P -> LDS (f32)
#pragma unroll
    for (int r = 0; r < 4; ++r) {
      float s0 = s[0][r] + mrow[(size_t)r * NTOK + k0];
      float s1 = s[1][r] + mrow[(size_t)r * NTOK + k0 + 16];
      float s2 = s[2][r] + mrow[(size_t)r * NTOK + k0 + 32];
      float s3 = s[3][r] + mrow[(size_t)r * NTOK + k0 + 48];
      float mx = fmaxf(fmaxf(s0, s1), fmaxf(s2, s3));
#pragma unroll
      for (int off = 1; off < 16; off <<= 1)
        mx = fmaxf(mx, __shfl_xor(mx, off, 16));
      float mnew = fmaxf(mst[r], mx);
      float corr = __expf(mst[r] - mnew);
      mst[r] = mnew;
      float p0 = __expf(s0 - mnew), p1 = __expf(s1 - mnew);
      float p2 = __expf(s2 - mnew), p3 = __expf(s3 - mnew);
      float rs = (p0 + p1) + (p2 + p3);
#pragma unroll
      for (int off = 1; off < 16; off <<= 1)
        rs += __shfl_xor(rs, off, 16);
      lst[r] = lst[r] * corr + rs;
      accd[0][r] *= corr;
      accd[1][r] *= corr;
      int prow = w * 16 + grp * 4 + r;
      Ps[prow][row16] = p0;
      Ps[prow][row16 + 16] = p1;
      Ps[prow][row16 + 32] = p2;
      Ps[prow][row16 + 48] = p3;
    }
    // ---- PV (wave-local LDS read-back; compiler inserts lgkm waits)
#pragma unroll
    for (int ks = 0; ks < 2; ++ks) {
      const float* prow = &Ps[w * 16 + row16][ks * 32 + grp * 8];
      float4 pa = *reinterpret_cast<const float4*>(prow);
      float4 pb = *reinterpret_cast<const float4*>(prow + 4);
      u16x8 hu, lu;
      float pv[8] = {pa.x, pa.y, pa.z, pa.w, pb.x, pb.y, pb.z, pb.w};
#pragma unroll
      for (int j = 0; j < 8; ++j) {
        unsigned u = __float_as_uint(pv[j]);
        hu[j] = (unsigned short)(u >> 16);
        float fl = pv[j] - __uint_as_float(u & 0xFFFF0000u);
        lu[j] = (unsigned short)(__float_as_uint(fl) >> 16);
      }
      bf16x8 phi = __builtin_bit_cast(bf16x8, hu);
      bf16x8 plo = __builtin_bit_cast(bf16x8, lu);
#pragma unroll
      for (int df = 0; df < 2; ++df) {
        size_t vidx = ((size_t)(df * 16 + row16)) * NTOK + k0 + ks * 32 + grp * 8;
        bf16x8 vh = ldb8(vbase_hi + vidx);
        bf16x8 vl = ldb8(vbase_lo + vidx);
        accd[df] = __builtin_amdgcn_mfma_f32_16x16x32_bf16(phi, vh, accd[df], 0, 0, 0);
        accd[df] = __builtin_amdgcn_mfma_f32_16x16x32_bf16(plo, vh, accd[df], 0, 0, 0);
        accd[df] = __builtin_amdgcn_mfma_f32_16x16x32_bf16(phi, vl, accd[df], 0, 0, 0);
      }
    }
  }
  // ---- epilogue
#pragma unroll
  for (int r = 0; r < 4; ++r) {
    float inv = 1.f / lst[r];
    int qrow = q0 + w * 16 + grp * 4 + r;
    size_t obase = ((size_t)b * NTOK + qrow) * CDIM + h * HD;
    o[obase + row16] = accd[0][r] * inv;
    o[obase + 16 + row16] = accd[1][r] * inv;
  }
}

// ---------------------------------------------------------------------------
// Output projection: aout(16384,256) @ Wp(256,256) + bp -> out (fp32)
// ---------------------------------------------------------------------------
__global__ __launch_bounds__(256) void gemm_out(
    const float* __restrict__ X, const float* __restrict__ W,
    const float* __restrict__ bp, float* __restrict__ out) {
  __shared__ float Xs[64][65];
  __shared__ float Ws[64][65];
  int tid = threadIdx.x;
  int m0 = blockIdx.y * 64;
  int j0 = blockIdx.x * 64;
  int lr = tid >> 4;
  int lc = (tid & 15) * 4;
  int tr = tid >> 4, tc = tid & 15;
  float acc[4][4] = {};
  for (int k0 = 0; k0 < CDIM; k0 += 64) {
    __syncthreads();
#pragma unroll
    for (int rr = 0; rr < 4; ++rr) {
      int row = lr + rr * 16;
      float4 xv = *(const float4*)(X + (size_t)(m0 + row) * CDIM + k0 + lc);
      Xs[row][lc] = xv.x; Xs[row][lc + 1] = xv.y;
      Xs[row][lc + 2] = xv.z; Xs[row][lc + 3] = xv.w;
      float4 wv = *(const float4*)(W + (size_t)(k0 + row) * CDIM + j0 + lc);
      Ws[row][lc] = wv.x; Ws[row][lc + 1] = wv.y;
      Ws[row][lc + 2] = wv.z; Ws[row][lc + 3] = wv.w;
    }
    __syncthreads();
#pragma unroll
    for (int kk = 0; kk < 64; ++kk) {
      float a0 = Xs[tr * 4 + 0][kk], a1 = Xs[tr * 4 + 1][kk];
      float a2 = Xs[tr * 4 + 2][kk], a3 = Xs[tr * 4 + 3][kk];
      float b0 = Ws[kk][tc * 4 + 0], b1 = Ws[kk][tc * 4 + 1];
      float b2 = Ws[kk][tc * 4 + 2], b3 = Ws[kk][tc * 4 + 3];
      acc[0][0] = fmaf(a0, b0, acc[0][0]); acc[0][1] = fmaf(a0, b1, acc[0][1]);
      acc[0][2] = fmaf(a0, b2, acc[0][2]); acc[0][3] = fmaf(a0, b3, acc[0][3]);
      acc[1][0] = fmaf(a1, b0, acc[1][0]); acc[1][1] = fmaf(a1, b1, acc[1][1]);
      acc[1][2] = fmaf(a1, b2, acc[1][2]); acc[1][3] = fmaf(a1, b3, acc[1][3]);
      acc[2][0] = fmaf(a2, b0, acc[2][0]); acc[2][1] = fmaf(a2, b1, acc[2][1]);
      acc[2][2] = fmaf(a2, b2, acc[2][2]); acc[2][3] = fmaf(a2, b3, acc[2][3]);
      acc[3][0] = fmaf(a3, b0, acc[3][0]); acc[3][1] = fmaf(a3, b1, acc[3][1]);
      acc[3][2] = fmaf(a3, b2, acc[3][2]); acc[3][3] = fmaf(a3, b3, acc[3][3]);
    }
  }
#pragma unroll
  for (int i = 0; i < 4; ++i) {
    int m = m0 + tr * 4 + i;
#pragma unroll
    for (int j = 0; j < 4; ++j) {
      int jg = j0 + tc * 4 + j;
      out[(size_t)m * CDIM + jg] = acc[i][j] + bp[jg];
    }
  }
}

// ---------------------------------------------------------------------------
extern "C" void kernel_launch(void* const* d_in, const int* in_sizes, int n_in,
                              void* d_out, int out_size, void* d_ws,
                              size_t ws_size, hipStream_t stream) {
  const float* x = (const float*)d_in[0];
  const float* mask = (const float*)d_in[1];
  const float* affine = (const float*)d_in[2];
  const float* Wq = (const float*)d_in[3];
  const float* bq = (const float*)d_in[4];
  const float* Wkv = (const float*)d_in[5];
  const float* bkv = (const float*)d_in[6];
  const float* Wp = (const float*)d_in[7];
  const float* bp = (const float*)d_in[8];
  const float* atab = (const float*)d_in[9];
  float* out = (float*)d_out;

  const size_t bhnd = (size_t)BB * HEADS * NTOK * HD;  // 4,194,304
  unsigned short* qhi = (unsigned short*)d_ws;
  unsigned short* qlo = qhi + bhnd;
  unsigned short* khi = qlo + bhnd;
  unsigned short* klo = khi + bhnd;
  unsigned short* vthi = klo + bhnd;
  unsigned short* vtlo = vthi + bhnd;
  float* aout = (float*)(vtlo + bhnd);
  float* bias = aout + (size_t)BB * NTOK * CDIM;

  bias_kernel<<<64, 256, 0, stream>>>(affine, atab, bias);
  gemm_qkv<<<dim3(12, 256), 256, 0, stream>>>(x, Wq, bq, Wkv, bkv, bias,
                                              qhi, qlo, khi, klo, vthi, vtlo);
  attn_mfma<<<dim3(16, 8, 16), 256, 0, stream>>>(qhi, qlo, khi, klo, vthi,
                                                 vtlo, mask, aout);
  gemm_out<<<dim3(4, 256), 256, 0, stream>>>(aout, Wp, bp, out);
}